// Round 1
// baseline (820.531 us; speedup 1.0000x reference)
//
#include <hip/hip_runtime.h>
#include <cstddef>

typedef short bf16x8 __attribute__((ext_vector_type(8)));   // 8 bf16 in 4 VGPRs
typedef float f32x4  __attribute__((ext_vector_type(4)));

namespace {
constexpr float QSCALE = 0.17677669529663687f;  // 32^-0.5, folded into wq/bq at prep

// ---- workspace layout (bytes) ----
constexpr size_t BQKV_OFF = 0;                        // ushort[576][384]  B_T for qkv, [wh|wl] split
constexpr size_t WOUT_OFF = 576 * 384 * 2;            // ushort[192][384]  B_T for wout
constexpr size_t BQG_OFF  = WOUT_OFF + 192 * 384 * 2; // float[576] head-grouped qkv bias

// ---- kernel A LDS layout (half/ushort indices) ----
constexpr int AXS   = 392;                    // A row stride (384+8 pad); 196 words %32=4 -> benign
constexpr int AX_H  = 0;                      // [72][392] x split (xh 0-191 | xl 192-383)
constexpr int Q2A_H = 72 * AXS;               // 28224: [6][72][32] q  (unpadded: read once/job)
constexpr int K2A_H = Q2A_H + 6 * 72 * 32;    // 42048: [6][72][40] k
constexpr int V2A_H = K2A_H + 6 * 72 * 40;    // 59328: [6][32][104] v^T (tokens padded to 96, zeroed)
constexpr int HALF_TOT = V2A_H + 6 * 32 * 104;// 79296 halfs = 158,592 B <= 160 KiB
// post-QKV aliases inside the dead x region:
//   float btabs[4968] at half 0..9935, then 8 wave-private P bufs [16][104]
constexpr int PB_H  = 828 * 6 * 2;            // 9936
constexpr int LDSA_BYTES = HALF_TOT * 2;      // 158,592
}

__device__ __forceinline__ unsigned short f2bf(float f) {
  unsigned int u = __builtin_bit_cast(unsigned int, f);
  return (unsigned short)((u + 0x7FFFu + ((u >> 16) & 1u)) >> 16);   // RNE
}
__device__ __forceinline__ float bf2f(unsigned short h) {
  unsigned int u = ((unsigned int)h) << 16;
  return __builtin_bit_cast(float, u);
}
__device__ __forceinline__ int moffv(int i) { return (i < 4) ? i * 16 : 56; }  // m-tiles {0,16,32,48,56}

// ---------------- prep: weights -> split-bf16 B_T layouts in ws ----------------
__global__ __launch_bounds__(256)
void prep_kernel(const float* __restrict__ wqkv, const float* __restrict__ bqkv,
                 const float* __restrict__ wout, unsigned char* __restrict__ ws) {
  int t = blockIdx.x * 256 + threadIdx.x;
  unsigned short* Bq = (unsigned short*)(ws + BQKV_OFF);
  unsigned short* Bo = (unsigned short*)(ws + WOUT_OFF);
  float* bqg = (float*)(ws + BQG_OFF);
  if (t < 576 * 384) {
    int n = t / 384, kk = t % 384;
    int ksrc = kk % 192, part = kk / 192;
    int h = n / 96, r96 = n % 96, kind = r96 / 32, d = r96 % 32;
    float w = wqkv[(size_t)ksrc * 576 + kind * 192 + h * 32 + d];
    if (kind == 0) w *= QSCALE;
    unsigned short hi = f2bf(w);
    Bq[t] = part ? f2bf(w - bf2f(hi)) : hi;
  } else if (t < 576 * 384 + 192 * 384) {
    int t2 = t - 576 * 384;
    int n = t2 / 384, kk = t2 % 384, ksrc = kk % 192, part = kk / 192;
    float w = wout[(size_t)ksrc * 192 + n];
    unsigned short hi = f2bf(w);
    Bo[t2] = part ? f2bf(w - bf2f(hi)) : hi;
  } else if (t < 576 * 384 + 192 * 384 + 576) {
    int n = t - (576 * 384 + 192 * 384);
    int h = n / 96, r96 = n % 96, kind = r96 / 32, d = r96 % 32;
    float b = bqkv[kind * 192 + h * 32 + d];
    if (kind == 0) b *= QSCALE;
    bqg[n] = b;
  }
}

// QKV for one wave: NM m-tiles x 3 n-tiles x all 3 p-groups.
// A-fragments hoisted to registers per K-region: 18(12) ds_read_b128 feed 54(36) MFMAs.
template<int NM>
__device__ __forceinline__ void qkv_wave(unsigned short* sm, const unsigned short* __restrict__ Bq,
                                         const float* __restrict__ bqg, int ntb3, int m0idx,
                                         int lanen, int quad) {
  #pragma unroll 1
  for (int p = 0; p < 3; ++p) {
    const int nbase = 192 * p;
    f32x4 acc[3][NM];
    #pragma unroll
    for (int nt = 0; nt < 3; ++nt)
      #pragma unroll
      for (int mi = 0; mi < NM; ++mi)
        acc[nt][mi] = (f32x4){0.f, 0.f, 0.f, 0.f};
    #pragma unroll 1
    for (int reg = 0; reg < 3; ++reg) {          // xh*wh, xh*wl, xl*wh
      const int ab = (reg == 2) ? 192 : 0;
      const int bb = (reg == 1) ? 192 : 0;
      bf16x8 a[NM][6];
      #pragma unroll
      for (int mi = 0; mi < NM; ++mi) {
        const unsigned short* ap = sm + AX_H + (moffv(m0idx + mi) + lanen) * AXS + ab + quad * 8;
        #pragma unroll
        for (int s = 0; s < 6; ++s)
          a[mi][s] = *(const bf16x8*)(ap + 32 * s);
      }
      #pragma unroll
      for (int nt = 0; nt < 3; ++nt) {
        const unsigned short* bp = Bq + (size_t)(nbase + (ntb3 + nt) * 16 + lanen) * 384 + bb + quad * 8;
        #pragma unroll
        for (int s = 0; s < 6; ++s) {
          bf16x8 bfr = *(const bf16x8*)(bp + 32 * s);
          #pragma unroll
          for (int mi = 0; mi < NM; ++mi)
            acc[nt][mi] = __builtin_amdgcn_mfma_f32_16x16x32_bf16(a[mi][s], bfr, acc[nt][mi], 0, 0, 0);
        }
      }
    }
    // epilogue: route tiles to Q/K/V LDS (wave-uniform branches)
    #pragma unroll 1
    for (int nt = 0; nt < 3; ++nt) {
      const int ng = ntb3 + nt;
      const float bias = bqg[nbase + ng * 16 + lanen];
      const int hh = 2 * p + (ng >= 6 ? 1 : 0);
      const int w96 = (ng % 6) * 16;
      #pragma unroll
      for (int mi = 0; mi < NM; ++mi) {
        const int mo = moffv(m0idx + mi);
        if (w96 < 64) {                          // q or k: row-major
          unsigned short* dst;
          int stride, d;
          if (w96 < 32) { dst = sm + Q2A_H + hh * 2304; stride = 32; d = w96 + lanen; }
          else          { dst = sm + K2A_H + hh * 2880; stride = 40; d = w96 - 32 + lanen; }
          #pragma unroll
          for (int r = 0; r < 4; ++r)
            dst[(mo + quad * 4 + r) * stride + d] = f2bf(acc[nt][mi][r] + bias);
        } else {                                 // v: transposed [32][104], 4-token pack
          const int d = w96 - 64 + lanen;
          ushort4 hv;
          hv.x = f2bf(acc[nt][mi][0] + bias); hv.y = f2bf(acc[nt][mi][1] + bias);
          hv.z = f2bf(acc[nt][mi][2] + bias); hv.w = f2bf(acc[nt][mi][3] + bias);
          *(ushort4*)(sm + V2A_H + hh * 3328 + d * 104 + mo + quad * 4) = hv;
        }
      }
    }
  }
}

// ---------------- kernel A: QKV (all heads) + attention, split-po -> out ----------------
__global__ __launch_bounds__(512, 2)
void attn_kernel(const float* __restrict__ x, const float* __restrict__ mask,
                 const float* __restrict__ btab, const unsigned char* __restrict__ ws,
                 float* __restrict__ out) {
  extern __shared__ unsigned short sm[];
  const int w = blockIdx.x, tid = threadIdx.x;
  const int lane = tid & 63, ty = tid >> 6;
  const int lanen = lane & 15, quad = lane >> 4;
  const int mrow = w % 30, tlat = w % 31, w31 = w / 31;
  const float* xw = x + (size_t)w * (72 * 192);
  const float* maskw = mask + (size_t)mrow * (72 * 72);
  const unsigned short* Bq = (const unsigned short*)(ws + BQKV_OFF);
  const float* bqg = (const float*)(ws + BQG_OFF);

  // ---- phase 1: stage x split; zero v^T region (pads persist as 0) ----
  for (int i = tid; i < 3456; i += 512) {             // 72*192/4 float4 jobs
    int r = i / 48, c4 = i % 48;
    float4 v = *(const float4*)(xw + r * 192 + c4 * 4);
    unsigned short h0 = f2bf(v.x), h1 = f2bf(v.y), h2 = f2bf(v.z), h3 = f2bf(v.w);
    ushort4 hv; hv.x = h0; hv.y = h1; hv.z = h2; hv.w = h3;
    ushort4 lv;
    lv.x = f2bf(v.x - bf2f(h0)); lv.y = f2bf(v.y - bf2f(h1));
    lv.z = f2bf(v.z - bf2f(h2)); lv.w = f2bf(v.w - bf2f(h3));
    *(ushort4*)(sm + AX_H + r * AXS + c4 * 4) = hv;
    *(ushort4*)(sm + AX_H + r * AXS + 192 + c4 * 4) = lv;
  }
  for (int i = tid; i < 9984; i += 512)               // zero V2 (6*32*104 halfs)
    ((unsigned int*)(sm + V2A_H))[i] = 0u;
  __syncthreads();

  // ---- phase 2: QKV for ALL 6 heads, one barrier ----
  {
    const int mg = ty >> 2, ntb3 = (ty & 3) * 3;      // 2 m-groups x 4 n-thirds
    if (mg == 0) qkv_wave<3>(sm, Bq, bqg, ntb3, 0, lanen, quad);
    else         qkv_wave<2>(sm, Bq, bqg, ntb3, 3, lanen, quad);
  }
  __syncthreads();

  // ---- phase 2.5: x region dead -> stage bias-table slice + zero P buffers ----
  float* btabs = (float*)sm;
  for (int i = tid; i < 4968; i += 512)               // btab[:, tlat, :]
    btabs[i] = btab[(size_t)(i / 6) * 186 + tlat * 6 + (i % 6)];
  for (int i = tid; i < 6656; i += 512)               // zero 8x[16][104] P bufs
    ((unsigned int*)(sm + PB_H))[i] = 0u;
  __syncthreads();

  // ---- phase 3: attention, 30 jobs (6 heads x 5 strips) over 8 waves ----
  unsigned short* pb = sm + PB_H + ty * 1664;         // wave-private [16][104]
  unsigned short* po = (unsigned short*)(out + (size_t)w * (72 * 192));  // split-po halfs
  #pragma unroll 1
  for (int j = ty; j < 30; j += 8) {
    const int hh = j / 5, mo = moffv(j % 5);
    const unsigned short* q2 = sm + Q2A_H + hh * 2304;
    const unsigned short* k2 = sm + K2A_H + hh * 2880;
    const unsigned short* v2 = sm + V2A_H + hh * 3328;

    // S = q k^T: 1 A-frag, 5 col-tiles {0,16,32,48,64} (tail cols 72-79 masked below)
    bf16x8 afr = *(const bf16x8*)(q2 + (mo + lanen) * 32 + quad * 8);
    f32x4 s[5];
    #pragma unroll
    for (int t = 0; t < 5; ++t) {
      int no = (t < 4) ? t * 16 : 64;
      bf16x8 bfr = *(const bf16x8*)(k2 + (no + lanen) * 40 + quad * 8);
      s[t] = (f32x4){0.f, 0.f, 0.f, 0.f};
      s[t] = __builtin_amdgcn_mfma_f32_16x16x32_bf16(afr, bfr, s[t], 0, 0, 0);
    }
    // bias (on-the-fly row map) + mask + softmax in C-layout registers
    float lg[5][4];
    #pragma unroll
    for (int t = 0; t < 5; ++t) {
      int ct = ((t < 4) ? t * 16 : 64) + lanen;
      #pragma unroll
      for (int r = 0; r < 4; ++r) {
        if (ct < 72) {
          int m = mo + quad * 4 + r;
          // P = ((m*72+ct)*60 + w31) % 5184, via 4320*m mod 5184 = 864*((6-m%6)%6)
          unsigned int e = (unsigned)(m % 6); e = e ? 6u - e : 0u;
          unsigned int T = 864u * e + 60u * (unsigned)ct + (unsigned)w31;
          if (T >= 5184u) T -= 5184u;
          unsigned int p1 = T / 72u, p2 = T - 72u * p1;
          unsigned int i1 = p1 / 12u, j1 = p1 - 12u * i1;
          unsigned int i2 = p2 / 12u, j2 = p2 - 12u * i2;
          int rowb = (int)((i1 + 6u * i2) * 23u + j1) - (int)j2 + 11;
          float bv = btabs[rowb * 6 + hh];
          lg[t][r] = s[t][r] + bv + maskw[m * 72 + ct];
        } else lg[t][r] = -1e30f;                 // kill tail garbage (incl. NaN)
      }
    }
    #pragma unroll
    for (int r = 0; r < 4; ++r) {
      float mx = fmaxf(fmaxf(fmaxf(lg[0][r], lg[1][r]), fmaxf(lg[2][r], lg[3][r])), lg[4][r]);
      #pragma unroll
      for (int o = 8; o > 0; o >>= 1) mx = fmaxf(mx, __shfl_xor(mx, o));
      float sum = 0.f;
      #pragma unroll
      for (int t = 0; t < 5; ++t) { lg[t][r] = __expf(lg[t][r] - mx); sum += lg[t][r]; }
      #pragma unroll
      for (int o = 8; o > 0; o >>= 1) sum += __shfl_xor(sum, o);
      float inv = 1.0f / sum;
      #pragma unroll
      for (int t = 0; t < 5; ++t) {
        int ct = ((t < 4) ? t * 16 : 64) + lanen;
        if (ct < 72) pb[(quad * 4 + r) * 104 + ct] = f2bf(lg[t][r] * inv);
      }
    }
    // O = P V  (P cols 72-95 persistent zeros; v^T tokens 72-95 zeros)
    f32x4 o2[2];
    o2[0] = (f32x4){0.f, 0.f, 0.f, 0.f}; o2[1] = (f32x4){0.f, 0.f, 0.f, 0.f};
    #pragma unroll
    for (int ks = 0; ks < 3; ++ks) {
      bf16x8 pfr = *(const bf16x8*)(pb + lanen * 104 + ks * 32 + quad * 8);
      #pragma unroll
      for (int n2 = 0; n2 < 2; ++n2) {
        bf16x8 vfr = *(const bf16x8*)(v2 + (n2 * 16 + lanen) * 104 + ks * 32 + quad * 8);
        o2[n2] = __builtin_amdgcn_mfma_f32_16x16x32_bf16(pfr, vfr, o2[n2], 0, 0, 0);
      }
    }
    // write po pre-split (hi|lo halves) -> outproj stages with a raw copy
    #pragma unroll
    for (int n2 = 0; n2 < 2; ++n2) {
      int col = hh * 32 + n2 * 16 + lanen;
      #pragma unroll
      for (int r = 0; r < 4; ++r) {
        int row = mo + quad * 4 + r;
        float v = o2[n2][r];
        unsigned short hi = f2bf(v);
        po[row * 384 + col] = hi;
        po[row * 384 + 192 + col] = f2bf(v - bf2f(hi));
      }
    }
  }
}

// ---------------- kernel B: out = po @ w_out + b_out (in-place on d_out) ----------------
__global__ __launch_bounds__(256, 2)
void outproj_kernel(const unsigned char* __restrict__ ws, const float* __restrict__ bout,
                    float* __restrict__ out) {
  __shared__ unsigned short Ax[72 * AXS];   // 56,448 B static -> 2 blocks/CU
  const int w = blockIdx.x, tid = threadIdx.x;
  const int lane = tid & 63, ty = tid >> 6;
  const int lanen = lane & 15, quad = lane >> 4;
  const unsigned short* Bo = (const unsigned short*)(ws + WOUT_OFF);
  float* rows = out + (size_t)w * (72 * 192);
  const unsigned short* rw = (const unsigned short*)rows;  // pre-split po from attn

  for (int i = tid; i < 3456; i += 256) {   // raw copy: global split -> LDS split layout
    int r = i / 48, c8 = i % 48;
    *(uint4*)(Ax + r * AXS + c8 * 8) = *(const uint4*)(rw + r * 384 + c8 * 8);
  }
  __syncthreads();

  const int ntb3 = ty * 3;                  // 4 waves x 3 n-tiles, all 5 m-tiles each
  f32x4 acc[3][5];
  #pragma unroll
  for (int nt = 0; nt < 3; ++nt)
    #pragma unroll
    for (int mi = 0; mi < 5; ++mi)
      acc[nt][mi] = (f32x4){0.f, 0.f, 0.f, 0.f};

  #pragma unroll 1
  for (int reg = 0; reg < 3; ++reg) {
    const int ab = (reg == 2) ? 192 : 0;
    const int bb = (reg == 1) ? 192 : 0;
    #pragma unroll 1
    for (int hk = 0; hk < 2; ++hk) {        // half-K batches keep A live-set at 60 VGPR
      bf16x8 a[5][3];
      #pragma unroll
      for (int mi = 0; mi < 5; ++mi) {
        const unsigned short* ap = Ax + (moffv(mi) + lanen) * AXS + ab + hk * 96 + quad * 8;
        #pragma unroll
        for (int s2 = 0; s2 < 3; ++s2)
          a[mi][s2] = *(const bf16x8*)(ap + 32 * s2);
      }
      #pragma unroll
      for (int nt = 0; nt < 3; ++nt) {
        const unsigned short* bp = Bo + (size_t)((ntb3 + nt) * 16 + lanen) * 384 + bb + hk * 96 + quad * 8;
        #pragma unroll
        for (int s2 = 0; s2 < 3; ++s2) {
          bf16x8 bfr = *(const bf16x8*)(bp + 32 * s2);
          #pragma unroll
          for (int mi = 0; mi < 5; ++mi)
            acc[nt][mi] = __builtin_amdgcn_mfma_f32_16x16x32_bf16(a[mi][s2], bfr, acc[nt][mi], 0, 0, 0);
        }
      }
    }
  }

  #pragma unroll 1
  for (int nt = 0; nt < 3; ++nt) {
    const float bias = bout[(ntb3 + nt) * 16 + lanen];
    #pragma unroll
    for (int mi = 0; mi < 5; ++mi) {
      const int mo = moffv(mi);
      #pragma unroll
      for (int r = 0; r < 4; ++r)
        rows[(mo + quad * 4 + r) * 192 + (ntb3 + nt) * 16 + lanen] = acc[nt][mi][r] + bias;
    }
  }
}

extern "C" void kernel_launch(void* const* d_in, const int* in_sizes, int n_in,
                              void* d_out, int out_size, void* d_ws, size_t ws_size,
                              hipStream_t stream) {
  const float* x    = (const float*)d_in[0];
  const float* mask = (const float*)d_in[1];
  const float* wqkv = (const float*)d_in[2];
  const float* bqkv = (const float*)d_in[3];
  const float* wout = (const float*)d_in[4];
  const float* bout = (const float*)d_in[5];
  const float* btab = (const float*)d_in[6];
  float* out = (float*)d_out;
  unsigned char* ws = (unsigned char*)d_ws;
  const int nwindows = in_sizes[0] / (72 * 192);   // 1860

  prep_kernel<<<dim3(1155), dim3(256), 0, stream>>>(wqkv, bqkv, wout, ws);

  (void)hipFuncSetAttribute((const void*)attn_kernel,
                            hipFuncAttributeMaxDynamicSharedMemorySize, LDSA_BYTES);
  attn_kernel<<<dim3(nwindows), dim3(512), LDSA_BYTES, stream>>>(x, mask, btab, ws, out);

  outproj_kernel<<<dim3(nwindows), dim3(256), 0, stream>>>(ws, bout, out);
}

// Round 2
// 815.051 us; speedup vs baseline: 1.0067x; 1.0067x over previous
//
#include <hip/hip_runtime.h>
#include <cstddef>

typedef short bf16x8 __attribute__((ext_vector_type(8)));   // 8 bf16 in 4 VGPRs
typedef float f32x4  __attribute__((ext_vector_type(4)));

namespace {
constexpr float QSCALE = 0.17677669529663687f;  // 32^-0.5, folded into wq/bq at prep

// ---- workspace layout (bytes) ----
constexpr size_t BQKV_OFF = 0;                        // ushort[576][384]  B_T for qkv, [wh|wl] split
constexpr size_t WOUT_OFF = 576 * 384 * 2;            // ushort[192][384]  B_T for wout
constexpr size_t BQG_OFF  = WOUT_OFF + 192 * 384 * 2; // float[576] head-grouped qkv bias

// ---- kernel A LDS layout (half/ushort indices) ----
constexpr int AXS   = 392;                    // A row stride (384+8 pad); 196 words %32=4 -> benign
constexpr int AX_H  = 0;                      // [72][392] x split (xh 0-191 | xl 192-383)
constexpr int Q2A_H = 72 * AXS;               // 28224: [6][72][32] q  (unpadded: read once/job)
constexpr int K2A_H = Q2A_H + 6 * 72 * 32;    // 42048: [6][72][40] k
constexpr int V2A_H = K2A_H + 6 * 72 * 40;    // 59328: [6][32][104] v^T (tokens padded to 96, zeroed)
constexpr int HALF_TOT = V2A_H + 6 * 32 * 104;// 79296 halfs = 158,592 B <= 160 KiB
// post-QKV aliases inside the dead x region:
//   float btabs[4968] at half 0..9935, then 8 wave-private P bufs [16][104]
constexpr int PB_H  = 828 * 6 * 2;            // 9936
constexpr int LDSA_BYTES = HALF_TOT * 2;      // 158,592
}

__device__ __forceinline__ unsigned short f2bf(float f) {
  unsigned int u = __builtin_bit_cast(unsigned int, f);
  return (unsigned short)((u + 0x7FFFu + ((u >> 16) & 1u)) >> 16);   // RNE
}
__device__ __forceinline__ float bf2f(unsigned short h) {
  unsigned int u = ((unsigned int)h) << 16;
  return __builtin_bit_cast(float, u);
}
__device__ __forceinline__ int moffv(int i) { return (i < 4) ? i * 16 : 56; }  // m-tiles {0,16,32,48,56}

// ---------------- prep: weights -> split-bf16 B_T layouts in ws ----------------
__global__ __launch_bounds__(256)
void prep_kernel(const float* __restrict__ wqkv, const float* __restrict__ bqkv,
                 const float* __restrict__ wout, unsigned char* __restrict__ ws) {
  int t = blockIdx.x * 256 + threadIdx.x;
  unsigned short* Bq = (unsigned short*)(ws + BQKV_OFF);
  unsigned short* Bo = (unsigned short*)(ws + WOUT_OFF);
  float* bqg = (float*)(ws + BQG_OFF);
  if (t < 576 * 384) {
    int n = t / 384, kk = t % 384;
    int ksrc = kk % 192, part = kk / 192;
    int h = n / 96, r96 = n % 96, kind = r96 / 32, d = r96 % 32;
    float w = wqkv[(size_t)ksrc * 576 + kind * 192 + h * 32 + d];
    if (kind == 0) w *= QSCALE;
    unsigned short hi = f2bf(w);
    Bq[t] = part ? f2bf(w - bf2f(hi)) : hi;
  } else if (t < 576 * 384 + 192 * 384) {
    int t2 = t - 576 * 384;
    int n = t2 / 384, kk = t2 % 384, ksrc = kk % 192, part = kk / 192;
    float w = wout[(size_t)ksrc * 192 + n];
    unsigned short hi = f2bf(w);
    Bo[t2] = part ? f2bf(w - bf2f(hi)) : hi;
  } else if (t < 576 * 384 + 192 * 384 + 576) {
    int n = t - (576 * 384 + 192 * 384);
    int h = n / 96, r96 = n % 96, kind = r96 / 32, d = r96 % 32;
    float b = bqkv[kind * 192 + h * 32 + d];
    if (kind == 0) b *= QSCALE;
    bqg[n] = b;
  }
}

// QKV for one wave: NM m-tiles x 3 n-tiles x all 3 p-groups.
// A-fragments hoisted to registers per K-region: 18(12) ds_read_b128 feed 54(36) MFMAs.
// Requires the waves_per_eu(2,2) budget (256 VGPR) so the hoist survives regalloc.
template<int NM>
__device__ __forceinline__ void qkv_wave(unsigned short* sm, const unsigned short* __restrict__ Bq,
                                         const float* __restrict__ bqg, int ntb3, int m0idx,
                                         int lanen, int quad) {
  #pragma unroll 1
  for (int p = 0; p < 3; ++p) {
    const int nbase = 192 * p;
    f32x4 acc[3][NM];
    #pragma unroll
    for (int nt = 0; nt < 3; ++nt)
      #pragma unroll
      for (int mi = 0; mi < NM; ++mi)
        acc[nt][mi] = (f32x4){0.f, 0.f, 0.f, 0.f};
    #pragma unroll 1
    for (int reg = 0; reg < 3; ++reg) {          // xh*wh, xh*wl, xl*wh
      const int ab = (reg == 2) ? 192 : 0;
      const int bb = (reg == 1) ? 192 : 0;
      bf16x8 a[NM][6];
      #pragma unroll
      for (int mi = 0; mi < NM; ++mi) {
        const unsigned short* ap = sm + AX_H + (moffv(m0idx + mi) + lanen) * AXS + ab + quad * 8;
        #pragma unroll
        for (int s = 0; s < 6; ++s)
          a[mi][s] = *(const bf16x8*)(ap + 32 * s);
      }
      #pragma unroll
      for (int nt = 0; nt < 3; ++nt) {
        const unsigned short* bp = Bq + (size_t)(nbase + (ntb3 + nt) * 16 + lanen) * 384 + bb + quad * 8;
        #pragma unroll
        for (int s = 0; s < 6; ++s) {
          bf16x8 bfr = *(const bf16x8*)(bp + 32 * s);
          #pragma unroll
          for (int mi = 0; mi < NM; ++mi)
            acc[nt][mi] = __builtin_amdgcn_mfma_f32_16x16x32_bf16(a[mi][s], bfr, acc[nt][mi], 0, 0, 0);
        }
      }
    }
    // epilogue: route tiles to Q/K/V LDS (wave-uniform branches)
    #pragma unroll 1
    for (int nt = 0; nt < 3; ++nt) {
      const int ng = ntb3 + nt;
      const float bias = bqg[nbase + ng * 16 + lanen];
      const int hh = 2 * p + (ng >= 6 ? 1 : 0);
      const int w96 = (ng % 6) * 16;
      #pragma unroll
      for (int mi = 0; mi < NM; ++mi) {
        const int mo = moffv(m0idx + mi);
        if (w96 < 64) {                          // q or k: row-major
          unsigned short* dst;
          int stride, d;
          if (w96 < 32) { dst = sm + Q2A_H + hh * 2304; stride = 32; d = w96 + lanen; }
          else          { dst = sm + K2A_H + hh * 2880; stride = 40; d = w96 - 32 + lanen; }
          #pragma unroll
          for (int r = 0; r < 4; ++r)
            dst[(mo + quad * 4 + r) * stride + d] = f2bf(acc[nt][mi][r] + bias);
        } else {                                 // v: transposed [32][104], 4-token pack
          const int d = w96 - 64 + lanen;
          ushort4 hv;
          hv.x = f2bf(acc[nt][mi][0] + bias); hv.y = f2bf(acc[nt][mi][1] + bias);
          hv.z = f2bf(acc[nt][mi][2] + bias); hv.w = f2bf(acc[nt][mi][3] + bias);
          *(ushort4*)(sm + V2A_H + hh * 3328 + d * 104 + mo + quad * 4) = hv;
        }
      }
    }
  }
}

// ---------------- kernel A: QKV (all heads) + attention, po(f32) -> out ----------------
__global__ __launch_bounds__(512)
__attribute__((amdgpu_waves_per_eu(2, 2)))   // LDS caps us at 1 block/CU = 2 waves/EU; unlock 256 VGPR
void attn_kernel(const float* __restrict__ x, const float* __restrict__ mask,
                 const float* __restrict__ btab, const unsigned char* __restrict__ ws,
                 float* __restrict__ out) {
  extern __shared__ unsigned short sm[];
  const int w = blockIdx.x, tid = threadIdx.x;
  const int lane = tid & 63, ty = tid >> 6;
  const int lanen = lane & 15, quad = lane >> 4;
  const int mrow = w % 30, tlat = w % 31, w31 = w / 31;
  const float* xw = x + (size_t)w * (72 * 192);
  const float* maskw = mask + (size_t)mrow * (72 * 72);
  const unsigned short* Bq = (const unsigned short*)(ws + BQKV_OFF);
  const float* bqg = (const float*)(ws + BQG_OFF);

  // ---- phase 1: stage x split; zero v^T region (pads persist as 0) ----
  for (int i = tid; i < 3456; i += 512) {             // 72*192/4 float4 jobs
    int r = i / 48, c4 = i % 48;
    float4 v = *(const float4*)(xw + r * 192 + c4 * 4);
    unsigned short h0 = f2bf(v.x), h1 = f2bf(v.y), h2 = f2bf(v.z), h3 = f2bf(v.w);
    ushort4 hv; hv.x = h0; hv.y = h1; hv.z = h2; hv.w = h3;
    ushort4 lv;
    lv.x = f2bf(v.x - bf2f(h0)); lv.y = f2bf(v.y - bf2f(h1));
    lv.z = f2bf(v.z - bf2f(h2)); lv.w = f2bf(v.w - bf2f(h3));
    *(ushort4*)(sm + AX_H + r * AXS + c4 * 4) = hv;
    *(ushort4*)(sm + AX_H + r * AXS + 192 + c4 * 4) = lv;
  }
  for (int i = tid; i < 9984; i += 512)               // zero V2 (6*32*104 halfs)
    ((unsigned int*)(sm + V2A_H))[i] = 0u;
  __syncthreads();

  // ---- phase 2: QKV for ALL 6 heads, one barrier ----
  {
    const int mg = ty >> 2, ntb3 = (ty & 3) * 3;      // 2 m-groups x 4 n-thirds
    if (mg == 0) qkv_wave<3>(sm, Bq, bqg, ntb3, 0, lanen, quad);
    else         qkv_wave<2>(sm, Bq, bqg, ntb3, 3, lanen, quad);
  }
  __syncthreads();

  // ---- phase 2.5: x region dead -> stage bias-table slice + zero P buffers ----
  float* btabs = (float*)sm;
  for (int i = tid; i < 4968; i += 512)               // btab[:, tlat, :]
    btabs[i] = btab[(size_t)(i / 6) * 186 + tlat * 6 + (i % 6)];
  for (int i = tid; i < 6656; i += 512)               // zero 8x[16][104] P bufs
    ((unsigned int*)(sm + PB_H))[i] = 0u;
  __syncthreads();

  // ---- phase 3: attention, 30 jobs (6 heads x 5 strips) over 8 waves ----
  unsigned short* pb = sm + PB_H + ty * 1664;         // wave-private [16][104]
  #pragma unroll 1
  for (int j = ty; j < 30; j += 8) {
    const int hh = j / 5, mo = moffv(j % 5);
    const unsigned short* q2 = sm + Q2A_H + hh * 2304;
    const unsigned short* k2 = sm + K2A_H + hh * 2880;
    const unsigned short* v2 = sm + V2A_H + hh * 3328;

    // S = q k^T: 1 A-frag, 5 col-tiles {0,16,32,48,64} (tail cols 72-79 masked below)
    bf16x8 afr = *(const bf16x8*)(q2 + (mo + lanen) * 32 + quad * 8);
    f32x4 s[5];
    #pragma unroll
    for (int t = 0; t < 5; ++t) {
      int no = (t < 4) ? t * 16 : 64;
      bf16x8 bfr = *(const bf16x8*)(k2 + (no + lanen) * 40 + quad * 8);
      s[t] = (f32x4){0.f, 0.f, 0.f, 0.f};
      s[t] = __builtin_amdgcn_mfma_f32_16x16x32_bf16(afr, bfr, s[t], 0, 0, 0);
    }
    // bias (on-the-fly row map) + mask + softmax in C-layout registers
    float lg[5][4];
    #pragma unroll
    for (int t = 0; t < 5; ++t) {
      int ct = ((t < 4) ? t * 16 : 64) + lanen;
      #pragma unroll
      for (int r = 0; r < 4; ++r) {
        if (ct < 72) {
          int m = mo + quad * 4 + r;
          // P = ((m*72+ct)*60 + w31) % 5184, via 4320*m mod 5184 = 864*((6-m%6)%6)
          unsigned int e = (unsigned)(m % 6); e = e ? 6u - e : 0u;
          unsigned int T = 864u * e + 60u * (unsigned)ct + (unsigned)w31;
          if (T >= 5184u) T -= 5184u;
          unsigned int p1 = T / 72u, p2 = T - 72u * p1;
          unsigned int i1 = p1 / 12u, j1 = p1 - 12u * i1;
          unsigned int i2 = p2 / 12u, j2 = p2 - 12u * i2;
          int rowb = (int)((i1 + 6u * i2) * 23u + j1) - (int)j2 + 11;
          float bv = btabs[rowb * 6 + hh];
          lg[t][r] = s[t][r] + bv + maskw[m * 72 + ct];
        } else lg[t][r] = -1e30f;                 // kill tail garbage (incl. NaN)
      }
    }
    #pragma unroll
    for (int r = 0; r < 4; ++r) {
      float mx = fmaxf(fmaxf(fmaxf(lg[0][r], lg[1][r]), fmaxf(lg[2][r], lg[3][r])), lg[4][r]);
      #pragma unroll
      for (int o = 8; o > 0; o >>= 1) mx = fmaxf(mx, __shfl_xor(mx, o));
      float sum = 0.f;
      #pragma unroll
      for (int t = 0; t < 5; ++t) { lg[t][r] = __expf(lg[t][r] - mx); sum += lg[t][r]; }
      #pragma unroll
      for (int o = 8; o > 0; o >>= 1) sum += __shfl_xor(sum, o);
      float inv = 1.0f / sum;
      #pragma unroll
      for (int t = 0; t < 5; ++t) {
        int ct = ((t < 4) ? t * 16 : 64) + lanen;
        if (ct < 72) pb[(quad * 4 + r) * 104 + ct] = f2bf(lg[t][r] * inv);
      }
    }
    // O = P V  (P cols 72-95 persistent zeros; v^T tokens 72-95 zeros)
    f32x4 o2[2];
    o2[0] = (f32x4){0.f, 0.f, 0.f, 0.f}; o2[1] = (f32x4){0.f, 0.f, 0.f, 0.f};
    #pragma unroll
    for (int ks = 0; ks < 3; ++ks) {
      bf16x8 pfr = *(const bf16x8*)(pb + lanen * 104 + ks * 32 + quad * 8);
      #pragma unroll
      for (int n2 = 0; n2 < 2; ++n2) {
        bf16x8 vfr = *(const bf16x8*)(v2 + (n2 * 16 + lanen) * 104 + ks * 32 + quad * 8);
        o2[n2] = __builtin_amdgcn_mfma_f32_16x16x32_bf16(pfr, vfr, o2[n2], 0, 0, 0);
      }
    }
    // write po as f32 (64B-contiguous per 16 lanes -> no HBM write amplification)
    #pragma unroll
    for (int n2 = 0; n2 < 2; ++n2) {
      int col = hh * 32 + n2 * 16 + lanen;
      #pragma unroll
      for (int r = 0; r < 4; ++r)
        out[((size_t)w * 72 + mo + quad * 4 + r) * 192 + col] = o2[n2][r];
    }
  }
}

// ---------------- kernel B: out = po @ w_out + b_out (in-place on d_out) ----------------
__global__ __launch_bounds__(256)
__attribute__((amdgpu_waves_per_eu(2, 2)))   // 56KB static LDS -> 2 blocks/CU = 2 waves/EU
void outproj_kernel(const unsigned char* __restrict__ ws, const float* __restrict__ bout,
                    float* __restrict__ out) {
  __shared__ unsigned short Ax[72 * AXS];   // 56,448 B static -> 2 blocks/CU
  const int w = blockIdx.x, tid = threadIdx.x;
  const int lane = tid & 63, ty = tid >> 6;
  const int lanen = lane & 15, quad = lane >> 4;
  const unsigned short* Bo = (const unsigned short*)(ws + WOUT_OFF);
  float* rows = out + (size_t)w * (72 * 192);

  for (int i = tid; i < 3456; i += 256) {   // stage po(f32) split into LDS
    int r = i / 48, c4 = i % 48;
    float4 v = *(const float4*)(rows + r * 192 + c4 * 4);
    unsigned short h0 = f2bf(v.x), h1 = f2bf(v.y), h2 = f2bf(v.z), h3 = f2bf(v.w);
    ushort4 hv; hv.x = h0; hv.y = h1; hv.z = h2; hv.w = h3;
    ushort4 lv;
    lv.x = f2bf(v.x - bf2f(h0)); lv.y = f2bf(v.y - bf2f(h1));
    lv.z = f2bf(v.z - bf2f(h2)); lv.w = f2bf(v.w - bf2f(h3));
    *(ushort4*)(Ax + r * AXS + c4 * 4) = hv;
    *(ushort4*)(Ax + r * AXS + 192 + c4 * 4) = lv;
  }
  __syncthreads();

  const int ntb3 = ty * 3;                  // 4 waves x 3 n-tiles, all 5 m-tiles each
  f32x4 acc[3][5];
  #pragma unroll
  for (int nt = 0; nt < 3; ++nt)
    #pragma unroll
    for (int mi = 0; mi < 5; ++mi)
      acc[nt][mi] = (f32x4){0.f, 0.f, 0.f, 0.f};

  #pragma unroll 1
  for (int reg = 0; reg < 3; ++reg) {
    const int ab = (reg == 2) ? 192 : 0;
    const int bb = (reg == 1) ? 192 : 0;
    #pragma unroll 1
    for (int hk = 0; hk < 2; ++hk) {        // half-K batches keep A live-set bounded
      bf16x8 a[5][3];
      #pragma unroll
      for (int mi = 0; mi < 5; ++mi) {
        const unsigned short* ap = Ax + (moffv(mi) + lanen) * AXS + ab + hk * 96 + quad * 8;
        #pragma unroll
        for (int s2 = 0; s2 < 3; ++s2)
          a[mi][s2] = *(const bf16x8*)(ap + 32 * s2);
      }
      #pragma unroll
      for (int nt = 0; nt < 3; ++nt) {
        const unsigned short* bp = Bo + (size_t)((ntb3 + nt) * 16 + lanen) * 384 + bb + hk * 96 + quad * 8;
        #pragma unroll
        for (int s2 = 0; s2 < 3; ++s2) {
          bf16x8 bfr = *(const bf16x8*)(bp + 32 * s2);
          #pragma unroll
          for (int mi = 0; mi < 5; ++mi)
            acc[nt][mi] = __builtin_amdgcn_mfma_f32_16x16x32_bf16(a[mi][s2], bfr, acc[nt][mi], 0, 0, 0);
        }
      }
    }
  }

  #pragma unroll 1
  for (int nt = 0; nt < 3; ++nt) {
    const float bias = bout[(ntb3 + nt) * 16 + lanen];
    #pragma unroll
    for (int mi = 0; mi < 5; ++mi) {
      const int mo = moffv(mi);
      #pragma unroll
      for (int r = 0; r < 4; ++r)
        rows[(mo + quad * 4 + r) * 192 + (ntb3 + nt) * 16 + lanen] = acc[nt][mi][r] + bias;
    }
  }
}

extern "C" void kernel_launch(void* const* d_in, const int* in_sizes, int n_in,
                              void* d_out, int out_size, void* d_ws, size_t ws_size,
                              hipStream_t stream) {
  const float* x    = (const float*)d_in[0];
  const float* mask = (const float*)d_in[1];
  const float* wqkv = (const float*)d_in[2];
  const float* bqkv = (const float*)d_in[3];
  const float* wout = (const float*)d_in[4];
  const float* bout = (const float*)d_in[5];
  const float* btab = (const float*)d_in[6];
  float* out = (float*)d_out;
  unsigned char* ws = (unsigned char*)d_ws;
  const int nwindows = in_sizes[0] / (72 * 192);   // 1860

  prep_kernel<<<dim3(1155), dim3(256), 0, stream>>>(wqkv, bqkv, wout, ws);

  (void)hipFuncSetAttribute((const void*)attn_kernel,
                            hipFuncAttributeMaxDynamicSharedMemorySize, LDSA_BYTES);
  attn_kernel<<<dim3(nwindows), dim3(512), LDSA_BYTES, stream>>>(x, mask, btab, ws, out);

  outproj_kernel<<<dim3(nwindows), dim3(256), 0, stream>>>(ws, bout, out);
}